// Round 5
// baseline (18.639 us; speedup 1.0000x reference)
//
#include <hip/hip_runtime.h>

// loss = (1/T) * (1 - mean_i p_i),  p_i = dot(a_i,b_i) / (max(||a_i||,eps)*max(||b_i||,eps))
// B=4096, D=512, T=0.5, eps=1e-12
//
// Structure: [memset 64B of d_ws to 0] -> [one kernel].
// The memset node re-zeroes the 8 float accumulator slots + counter EVERY call,
// so there is no cross-call state and no poison sensitivity.
// Each block reduces its 16 rows, atomicAdd_f32 (relaxed, agent) into slot
// (blockIdx&7), s_waitcnt vmcnt(0) to order, then counter fetch_add; the block
// that sees old==NBLOCKS-1 sums the 8 slots (all complete by then: every
// block's slot-add is globally visible before its counter-inc) and writes the
// loss. Relaxed atomics execute at the coherent point (L3) -- no wbl2/inv ops,
// which is what made round 3's __threadfence version slow.
// Float-atomic ordering varies run-to-run by ~1e-6 -- far under the 4e-2
// threshold.

#define BATCH 4096
#define DIM 512
#define THREADS 512            // 8 waves/block
#define WAVES_PER_BLOCK 8
#define ROWS_PER_WAVE 2
#define ROWS_PER_BLOCK (WAVES_PER_BLOCK * ROWS_PER_WAVE)   // 16
#define NBLOCKS (BATCH / ROWS_PER_BLOCK)                   // 256
#define NSLOTS 8

__global__ void __launch_bounds__(THREADS)
fused_contrastive_loss(const float* __restrict__ a,
                       const float* __restrict__ b,
                       float* __restrict__ out,
                       float* __restrict__ acc,          // [NSLOTS]
                       unsigned int* __restrict__ cnt) { // [1]
    const int wave = threadIdx.x >> 6;          // 0..7
    const int lane = threadIdx.x & 63;
    const int r0   = (blockIdx.x * WAVES_PER_BLOCK + wave) * ROWS_PER_WAVE;

    // Each wave handles rows r0, r0+1. Row = 128 float4. Lane l covers
    // float4[l], float4[l+64] of each row -> 8 independent 16B loads/thread.
    const float4* a4 = reinterpret_cast<const float4*>(a) + (size_t)r0 * (DIM / 4);
    const float4* b4 = reinterpret_cast<const float4*>(b) + (size_t)r0 * (DIM / 4);

    float4 av0 = a4[lane];
    float4 av1 = a4[lane + 64];
    float4 av2 = a4[lane + 128];
    float4 av3 = a4[lane + 192];
    float4 bv0 = b4[lane];
    float4 bv1 = b4[lane + 64];
    float4 bv2 = b4[lane + 128];
    float4 bv3 = b4[lane + 192];

    // row r0
    float dot0 = av0.x*bv0.x + av0.y*bv0.y + av0.z*bv0.z + av0.w*bv0.w
               + av1.x*bv1.x + av1.y*bv1.y + av1.z*bv1.z + av1.w*bv1.w;
    float na0  = av0.x*av0.x + av0.y*av0.y + av0.z*av0.z + av0.w*av0.w
               + av1.x*av1.x + av1.y*av1.y + av1.z*av1.z + av1.w*av1.w;
    float nb0  = bv0.x*bv0.x + bv0.y*bv0.y + bv0.z*bv0.z + bv0.w*bv0.w
               + bv1.x*bv1.x + bv1.y*bv1.y + bv1.z*bv1.z + bv1.w*bv1.w;
    // row r0+1
    float dot1 = av2.x*bv2.x + av2.y*bv2.y + av2.z*bv2.z + av2.w*bv2.w
               + av3.x*bv3.x + av3.y*bv3.y + av3.z*bv3.z + av3.w*bv3.w;
    float na1  = av2.x*av2.x + av2.y*av2.y + av2.z*av2.z + av2.w*av2.w
               + av3.x*av3.x + av3.y*av3.y + av3.z*av3.z + av3.w*av3.w;
    float nb1  = bv2.x*bv2.x + bv2.y*bv2.y + bv2.z*bv2.z + bv2.w*bv2.w
               + bv3.x*bv3.x + bv3.y*bv3.y + bv3.z*bv3.z + bv3.w*bv3.w;

    #pragma unroll
    for (int off = 32; off > 0; off >>= 1) {
        dot0 += __shfl_xor(dot0, off);
        na0  += __shfl_xor(na0, off);
        nb0  += __shfl_xor(nb0, off);
        dot1 += __shfl_xor(dot1, off);
        na1  += __shfl_xor(na1, off);
        nb1  += __shfl_xor(nb1, off);
    }

    __shared__ float s[WAVES_PER_BLOCK];
    if (lane == 0) {
        float d0 = fmaxf(sqrtf(na0), 1e-12f) * fmaxf(sqrtf(nb0), 1e-12f);
        float d1 = fmaxf(sqrtf(na1), 1e-12f) * fmaxf(sqrtf(nb1), 1e-12f);
        s[wave] = dot0 / d0 + dot1 / d1;
    }
    __syncthreads();

    if (threadIdx.x == 0) {
        float p = 0.f;
        #pragma unroll
        for (int i = 0; i < WAVES_PER_BLOCK; ++i) p += s[i];

        // 1) publish partial into one of 8 slots (relaxed agent atomic -> L3)
        __hip_atomic_fetch_add(&acc[blockIdx.x & (NSLOTS - 1)], p,
                               __ATOMIC_RELAXED, __HIP_MEMORY_SCOPE_AGENT);
        // 2) ensure the slot-add is globally performed before counter-inc
        asm volatile("s_waitcnt vmcnt(0)" ::: "memory");
        // 3) arrival counter
        unsigned int old = __hip_atomic_fetch_add(cnt, 1u,
                               __ATOMIC_RELAXED, __HIP_MEMORY_SCOPE_AGENT);
        if (old == NBLOCKS - 1) {
            // all 256 slot-adds are at L3; read them back in fixed slot order
            float sum_p = 0.f;
            #pragma unroll
            for (int i = 0; i < NSLOTS; ++i) {
                sum_p += __hip_atomic_load(&acc[i], __ATOMIC_RELAXED,
                                           __HIP_MEMORY_SCOPE_AGENT);
            }
            float mean_p = sum_p / (float)BATCH;
            out[0] = (1.0f - mean_p) * 2.0f;   // (1 - mean_p) / 0.5
        }
    }
}

extern "C" void kernel_launch(void* const* d_in, const int* in_sizes, int n_in,
                              void* d_out, int out_size, void* d_ws, size_t ws_size,
                              hipStream_t stream) {
    const float* a = (const float*)d_in[0];   // emb_i [B, D]
    const float* b = (const float*)d_in[1];   // emb_j [B, D]
    float* out = (float*)d_out;
    float* acc = (float*)d_ws;                              // 8 floats
    unsigned int* cnt = (unsigned int*)((char*)d_ws + 32);  // 1 uint

    // zero accumulators + counter every call (memset node precedes the kernel
    // on the critical path but executes in <1us for 64B)
    hipMemsetAsync(d_ws, 0, 64, stream);
    fused_contrastive_loss<<<NBLOCKS, THREADS, 0, stream>>>(a, b, out, acc, cnt);
}

// Round 6
// 11.232 us; speedup vs baseline: 1.6595x; 1.6595x over previous
//
#include <hip/hip_runtime.h>

// loss = (1/T) * (1 - mean_i p_i),  p_i = dot(a_i,b_i) / (max(||a_i||,eps)*max(||b_i||,eps))
// B=4096, D=512, T=0.5, eps=1e-12
//
// Two plain graph nodes (R1 structure, trimmed):
//  kernel 1: 256 blocks x 512 threads, 2 rows/wave, no LDS/barrier --
//            each wave's lane 0 stores its pair-cosine sum to partial[wave_id]
//  kernel 2: 1 block x 512 threads, each thread one float4 of the 2048
//            partials, butterfly reduce, write loss.
// All reduction orders fixed -> bit-deterministic. No cross-call state.

#define BATCH 4096
#define DIM 512
#define THREADS 512            // 8 waves/block
#define WAVES_PER_BLOCK 8
#define ROWS_PER_WAVE 2
#define ROWS_PER_BLOCK (WAVES_PER_BLOCK * ROWS_PER_WAVE)   // 16
#define NBLOCKS (BATCH / ROWS_PER_BLOCK)                   // 256
#define NPART (NBLOCKS * WAVES_PER_BLOCK)                  // 2048

__global__ void __launch_bounds__(THREADS)
pair_cosine_partial(const float* __restrict__ a,
                    const float* __restrict__ b,
                    float* __restrict__ partial) {
    const int wave = threadIdx.x >> 6;          // 0..7
    const int lane = threadIdx.x & 63;
    const int gw   = blockIdx.x * WAVES_PER_BLOCK + wave;   // global wave id
    const int r0   = gw * ROWS_PER_WAVE;

    // Each wave handles rows r0, r0+1. Row = 128 float4. Lane l covers
    // float4[l], float4[l+64] of each row -> 8 independent 16B loads/thread.
    const float4* a4 = reinterpret_cast<const float4*>(a) + (size_t)r0 * (DIM / 4);
    const float4* b4 = reinterpret_cast<const float4*>(b) + (size_t)r0 * (DIM / 4);

    float4 av0 = a4[lane];
    float4 av1 = a4[lane + 64];
    float4 av2 = a4[lane + 128];
    float4 av3 = a4[lane + 192];
    float4 bv0 = b4[lane];
    float4 bv1 = b4[lane + 64];
    float4 bv2 = b4[lane + 128];
    float4 bv3 = b4[lane + 192];

    // row r0
    float dot0 = av0.x*bv0.x + av0.y*bv0.y + av0.z*bv0.z + av0.w*bv0.w
               + av1.x*bv1.x + av1.y*bv1.y + av1.z*bv1.z + av1.w*bv1.w;
    float na0  = av0.x*av0.x + av0.y*av0.y + av0.z*av0.z + av0.w*av0.w
               + av1.x*av1.x + av1.y*av1.y + av1.z*av1.z + av1.w*av1.w;
    float nb0  = bv0.x*bv0.x + bv0.y*bv0.y + bv0.z*bv0.z + bv0.w*bv0.w
               + bv1.x*bv1.x + bv1.y*bv1.y + bv1.z*bv1.z + bv1.w*bv1.w;
    // row r0+1
    float dot1 = av2.x*bv2.x + av2.y*bv2.y + av2.z*bv2.z + av2.w*bv2.w
               + av3.x*bv3.x + av3.y*bv3.y + av3.z*bv3.z + av3.w*bv3.w;
    float na1  = av2.x*av2.x + av2.y*av2.y + av2.z*av2.z + av2.w*av2.w
               + av3.x*av3.x + av3.y*av3.y + av3.z*av3.z + av3.w*av3.w;
    float nb1  = bv2.x*bv2.x + bv2.y*bv2.y + bv2.z*bv2.z + bv2.w*bv2.w
               + bv3.x*bv3.x + bv3.y*bv3.y + bv3.z*bv3.z + bv3.w*bv3.w;

    #pragma unroll
    for (int off = 32; off > 0; off >>= 1) {
        dot0 += __shfl_xor(dot0, off);
        na0  += __shfl_xor(na0, off);
        nb0  += __shfl_xor(nb0, off);
        dot1 += __shfl_xor(dot1, off);
        na1  += __shfl_xor(na1, off);
        nb1  += __shfl_xor(nb1, off);
    }

    if (lane == 0) {
        float d0 = fmaxf(sqrtf(na0), 1e-12f) * fmaxf(sqrtf(nb0), 1e-12f);
        float d1 = fmaxf(sqrtf(na1), 1e-12f) * fmaxf(sqrtf(nb1), 1e-12f);
        partial[gw] = dot0 / d0 + dot1 / d1;
    }
}

__global__ void __launch_bounds__(THREADS)
finalize_loss(const float* __restrict__ partial,
              float* __restrict__ out) {
    // 2048 partials = 512 float4; thread t loads float4[t]
    const int t = threadIdx.x;
    const int lane = t & 63;
    const int wave = t >> 6;

    float4 v4 = reinterpret_cast<const float4*>(partial)[t];
    float v = v4.x + v4.y + v4.z + v4.w;

    #pragma unroll
    for (int off = 32; off > 0; off >>= 1) {
        v += __shfl_xor(v, off);
    }

    __shared__ float s[WAVES_PER_BLOCK];
    if (lane == 0) s[wave] = v;
    __syncthreads();
    if (t == 0) {
        float sum_p = 0.f;
        #pragma unroll
        for (int i = 0; i < WAVES_PER_BLOCK; ++i) sum_p += s[i];
        float mean_p = sum_p / (float)BATCH;
        out[0] = (1.0f - mean_p) * 2.0f;   // (1 - mean_p) / 0.5
    }
}

extern "C" void kernel_launch(void* const* d_in, const int* in_sizes, int n_in,
                              void* d_out, int out_size, void* d_ws, size_t ws_size,
                              hipStream_t stream) {
    const float* a = (const float*)d_in[0];   // emb_i [B, D]
    const float* b = (const float*)d_in[1];   // emb_j [B, D]
    float* out = (float*)d_out;
    float* partial = (float*)d_ws;            // NPART floats (8 KB)

    pair_cosine_partial<<<NBLOCKS, THREADS, 0, stream>>>(a, b, partial);
    finalize_loss<<<1, THREADS, 0, stream>>>(partial, out);
}